// Round 10
// baseline (102.870 us; speedup 1.0000x reference)
//
#include <hip/hip_runtime.h>

// Flash-attention fwd, causal GQA, paged KV. fp32 in/out, bf16 MFMA compute.
// Round 10: ZERO-BARRIER independent-warp design.
//  - prep packs K/V into fragment-major records: frag f, lane l -> contiguous
//    16B; kernel loads MFMA fragments DIRECTLY global->reg (coalesced 1KB/instr,
//    L1 absorbs 4-warp reuse). No K/V LDS, no __syncthreads at all.
//  - Q lives in per-warp LDS (8KB, XOR-swizzled, written once; intra-wave
//    lgkmcnt ordering only).
//  - V fragment loads group-pipelined (2 groups in flight), issued pre-softmax.
// Core: 32x32 swapped MFMA, in-reg softmax (permlane32_swap), T12 cvt_pk,
// T13 defer-max, qc-descending grid (LPT), __launch_bounds__(256,2) (proven
// no-spill budget).

#define SEQ   1024
#define NHQ   32
#define NHK   8
#define DH    128
#define BSZ   256
#define NBLK  16
#define QBLK  128
#define KVBLK 64
#define SCALE  0.0883883476483184f           // 1/sqrt(128)
#define SCLOG2 0.12752551286084812f          // SCALE * log2(e)

typedef __attribute__((ext_vector_type(8)))  short bf16x8;
typedef __attribute__((ext_vector_type(4)))  float f32x4;
typedef __attribute__((ext_vector_type(16))) float f32x16;
typedef __attribute__((ext_vector_type(2)))  unsigned int u32x2;
typedef unsigned short u16;
typedef unsigned int u32;
typedef unsigned long long u64;

static __device__ __forceinline__ u16 f2bf(float f) {
  union { float f; u32 u; } x; x.f = f;
  return (u16)((x.u + 0x7fffu + ((x.u >> 16) & 1u)) >> 16);  // RNE
}

static __device__ __forceinline__ u32 cvtpk(float a, float b) {
  u32 r;
  asm("v_cvt_pk_bf16_f32 %0, %1, %2" : "=v"(r) : "v"(a), "v"(b));
  return r;
}

// ---------------- preprocess: fp32 KV -> bf16 fragment-major records ----------------
// K_frag per (nb,hk,t4): 16 frags (f=kb*8+dc) x 64 lanes x 8 elems (8192 u16).
//   lane(hi,ln) record = K[t4*64 + kb*32 + ln][dc*16 + hi*8 + 0..7]
// V_frag per (nb,hk,t4): 16 frags (f=kc*4+db) x 64 lanes x 8 elems.
//   lane(hi,ln) record[j] = V[t4*64 + kc*16 + hi*8 + j][db*32 + ln]
__global__ void prep_kv(const float* __restrict__ kc_, const float* __restrict__ vc_,
                        u16* __restrict__ kfo, u16* __restrict__ vfo) {
  const int idx = blockIdx.x * 256 + threadIdx.x;   // (nb, key, hk, d4), d4 fastest
  const int d4  = idx & 31;
  const int hk  = (idx >> 5) & 7;
  const int key = (idx >> 8) & 255;
  const int nb  = idx >> 16;
  f32x4 kx = *(const f32x4*)(kc_ + (size_t)idx * 4);
  f32x4 vx = *(const f32x4*)(vc_ + (size_t)idx * 4);

  const int t4 = key >> 6;
  const size_t tbase = ((size_t)(nb * NHK + hk) * 4 + t4) * 8192;

  // K record piece: 4 consecutive d at d = 4*d4
  {
    const int kb = (key >> 5) & 1;
    const int ln = key & 31;
    const int dc = d4 >> 2;
    const int hi = (d4 >> 1) & 1;
    const int j0 = (d4 & 1) * 4;
    u64 pk = (u64)f2bf(kx[0]) | ((u64)f2bf(kx[1]) << 16) |
             ((u64)f2bf(kx[2]) << 32) | ((u64)f2bf(kx[3]) << 48);
    *(u64*)(kfo + tbase + (size_t)(kb * 8 + dc) * 512 + (hi * 32 + ln) * 8 + j0) = pk;
  }
  // V record pieces: 4 scattered 2B (key supplies frag row j)
  {
    const int wn = key & 63;
    const int kcw = wn >> 4;
    const int vhi = (wn >> 3) & 1;
    const int jj  = wn & 7;
#pragma unroll
    for (int j = 0; j < 4; ++j) {
      const int d  = d4 * 4 + j;
      const int db = d >> 5;
      const int vl = d & 31;
      vfo[tbase + (size_t)(kcw * 4 + db) * 512 + (vhi * 32 + vl) * 8 + jj] = f2bf(vx[j]);
    }
  }
}

// ---------------- main attention: 4 INDEPENDENT warps x 32 q-rows ----------------
__global__ __launch_bounds__(256, 2)
void attn_fwd_pre(const float* __restrict__ qg,
                  const u16* __restrict__ kfg,
                  const u16* __restrict__ vfg,
                  const int* __restrict__ btab,
                  float* __restrict__ outg)
{
  __shared__ u16 qlds[4][32 * 128];   // 32 KB: per-warp Q, XOR-swizzled (&15)

  const int tid  = threadIdx.x;
  const int lane = tid & 63;
  const int w    = tid >> 6;     // 0..3
  const int ln   = lane & 31;
  const int hi   = lane >> 5;
  const int bid  = blockIdx.x;   // 0..1023, qc-descending (LPT)

  const int qc = 7 - (bid >> 7);
  const int rr = bid & 127;
  const int hq = rr >> 2;
  const int b  = rr & 3;
  const int hk = hq >> 2;

  const int rg = qc * QBLK + w * 32 + ln;      // this lane's q-row (absolute)
  u16* qw = &qlds[w][0];

  // ---- prologue: Q row -> per-warp LDS (scaled, bf16, swizzled). No barrier:
  // only this wave reads its region; lgkmcnt orders write->read. ----
  {
    const float* qp = qg + ((size_t)(b * SEQ + rg) * NHQ + hq) * DH;
#pragma unroll
    for (int dcw = 0; dcw < 8; ++dcw) {
      const int d0w = hi * 64 + dcw * 8;
      f32x4 x0 = *(const f32x4*)(qp + d0w);
      f32x4 x1 = *(const f32x4*)(qp + d0w + 4);
      bf16x8 f;
#pragma unroll
      for (int j = 0; j < 4; ++j) {
        f[j]     = (short)f2bf(x0[j] * SCLOG2);
        f[j + 4] = (short)f2bf(x1[j] * SCLOG2);
      }
      *(bf16x8*)&qw[ln * 128 + (d0w ^ ((ln & 15) * 8))] = f;
    }
  }

  f32x16 o[4];
#pragma unroll
  for (int db = 0; db < 4; ++db)
#pragma unroll
    for (int i = 0; i < 16; ++i) o[db][i] = 0.f;
  float m = -1e30f, l = 0.f;

  const int tmaxw = 2 * qc + (w >> 1);   // last tile this warp computes

  for (int t = 0; t <= tmaxw; ++t) {
    const int nb = btab[b * (SEQ / BSZ) + (t >> 2)];
    const size_t tbase = ((size_t)(nb * NHK + hk) * 4 + (t & 3)) * 8192;
    const u16* kf = kfg + tbase + lane * 8;
    const u16* vf = vfg + tbase + lane * 8;

    // ---- S^T = K·Q (swapped): K frags direct global->reg, Q from LDS ----
    f32x16 sa[2];
    __builtin_amdgcn_s_setprio(1);
#pragma unroll
    for (int kb = 0; kb < 2; ++kb) {
      bf16x8 kr[8];
#pragma unroll
      for (int dc = 0; dc < 8; ++dc)
        kr[dc] = *(const bf16x8*)(kf + (size_t)(kb * 8 + dc) * 512);
      f32x16 acc;
#pragma unroll
      for (int i = 0; i < 16; ++i) acc[i] = 0.f;
#pragma unroll
      for (int dc = 0; dc < 8; ++dc) {
        const int d0 = dc * 16 + hi * 8;
        bf16x8 qr = *(const bf16x8*)&qw[ln * 128 + (d0 ^ ((ln & 15) * 8))];
        acc = __builtin_amdgcn_mfma_f32_32x32x16_bf16(kr[dc], qr, acc, 0, 0, 0);
      }
      sa[kb] = acc;
    }
    __builtin_amdgcn_s_setprio(0);

    // ---- V groups 0,1 in flight; latency hides under mask+softmax ----
    bf16x8 vbuf[2][4];
#pragma unroll
    for (int g = 0; g < 2; ++g)
#pragma unroll
      for (int db = 0; db < 4; ++db)
        vbuf[g][db] = *(const bf16x8*)(vf + (size_t)(g * 4 + db) * 512);

    // ---- causal mask (diagonal tile only) ----
    if (t == tmaxw) {
      const int kt = t * KVBLK;
#pragma unroll
      for (int kb = 0; kb < 2; ++kb)
#pragma unroll
        for (int r = 0; r < 16; ++r) {
          const int kglob = kt + kb * 32 + (r & 3) + 8 * (r >> 2) + 4 * hi;
          if (kglob > rg) sa[kb][r] = -1e30f;
        }
    }

    // ---- row max: max3-friendly tree + one partner swap ----
    float mx[8];
#pragma unroll
    for (int i = 0; i < 8; ++i)
      mx[i] = fmaxf(fmaxf(sa[0][i], sa[0][i + 8]), fmaxf(sa[1][i], sa[1][i + 8]));
    float m0 = fmaxf(fmaxf(mx[0], mx[1]), fmaxf(mx[2], mx[3]));
    float m1 = fmaxf(fmaxf(mx[4], mx[5]), fmaxf(mx[6], mx[7]));
    m0 = fmaxf(m0, m1);
    u32x2 xr = __builtin_amdgcn_permlane32_swap(
        __float_as_uint(m0), __float_as_uint(m0), false, false);
    const float tmax = fmaxf(__uint_as_float(xr[0]), __uint_as_float(xr[1]));

    // ---- deferred rescale (T13; log2 domain) ----
    if (tmax > m + 11.0f) {
      const float corr = exp2f(m - tmax);
      m = tmax;
      l *= corr;
#pragma unroll
      for (int db = 0; db < 4; ++db)
#pragma unroll
        for (int i = 0; i < 16; ++i) o[db][i] *= corr;
    }

    // ---- P = 2^(s - m); row sum (in-lane tree + partner swap) ----
    float sm[16];
#pragma unroll
    for (int i = 0; i < 16; ++i) {
      sa[0][i] = exp2f(sa[0][i] - m);
      sa[1][i] = exp2f(sa[1][i] - m);
      sm[i] = sa[0][i] + sa[1][i];
    }
#pragma unroll
    for (int st = 8; st >= 1; st >>= 1)
#pragma unroll
      for (int i = 0; i < st; ++i) sm[i] += sm[i + st];
    u32x2 sr = __builtin_amdgcn_permlane32_swap(
        __float_as_uint(sm[0]), __float_as_uint(sm[0]), false, false);
    l += __uint_as_float(sr[0]) + __uint_as_float(sr[1]);

    // ---- PV: O^T += V^T·P^T ; V groups pipelined 2-deep (T12 cvt_pk) ----
#pragma unroll
    for (int kc = 0; kc < 4; ++kc) {
      const int kb = kc >> 1, cc = kc & 1;
      const u32 x0 = cvtpk(sa[kb][8 * cc + 0], sa[kb][8 * cc + 1]);
      const u32 y0 = cvtpk(sa[kb][8 * cc + 4], sa[kb][8 * cc + 5]);
      const u32 x1 = cvtpk(sa[kb][8 * cc + 2], sa[kb][8 * cc + 3]);
      const u32 y1 = cvtpk(sa[kb][8 * cc + 6], sa[kb][8 * cc + 7]);
      u32x2 r0 = __builtin_amdgcn_permlane32_swap(x0, y0, false, false);
      u32x2 r1 = __builtin_amdgcn_permlane32_swap(x1, y1, false, false);
      union { bf16x8 v; u32 u[4]; } pb;
      pb.u[0] = r0[0]; pb.u[1] = r1[0]; pb.u[2] = r0[1]; pb.u[3] = r1[1];
      __builtin_amdgcn_s_setprio(1);
#pragma unroll
      for (int db = 0; db < 4; ++db)
        o[db] = __builtin_amdgcn_mfma_f32_32x32x16_bf16(vbuf[kc & 1][db], pb.v, o[db], 0, 0, 0);
      __builtin_amdgcn_s_setprio(0);
      if (kc < 2) {
#pragma unroll
        for (int db = 0; db < 4; ++db)
          vbuf[kc & 1][db] = *(const bf16x8*)(vf + (size_t)((kc + 2) * 4 + db) * 512);
      }
    }
  }

  // ---- epilogue: O[rg][d] / l ; d = db*32 + (reg&3) + 8*(reg>>2) + 4*hi ----
  const float inv = 1.0f / l;
  float* op = outg + ((size_t)(b * SEQ + rg) * NHQ + hq) * DH;
#pragma unroll
  for (int db = 0; db < 4; ++db)
#pragma unroll
    for (int q4 = 0; q4 < 4; ++q4) {
      f32x4 val;
#pragma unroll
      for (int r2 = 0; r2 < 4; ++r2) val[r2] = o[db][q4 * 4 + r2] * inv;
      *(f32x4*)(op + db * 32 + q4 * 8 + hi * 4) = val;
    }
}

// ---------------- fallback (fp32 caches, no ws), round-1 structure ----------------
__global__ __launch_bounds__(256, 2)
void attn_fwd_fb(const float* __restrict__ qg,
                 const float* __restrict__ kcache,
                 const float* __restrict__ vcache,
                 const int*   __restrict__ btab,
                 float* __restrict__ outg)
{
  __shared__ u16 lk[KVBLK * DH];
  __shared__ u16 lv[DH * KVBLK];
  __shared__ u16 lp[4][16 * KVBLK];

  const int tid  = threadIdx.x;
  const int lane = tid & 63;
  const int w    = tid >> 6;
  const int qt   = blockIdx.x;
  const int hq   = blockIdx.y;
  const int b    = blockIdx.z;
  const int hk   = hq >> 2;
  const int qbase = qt * 64;
  const int cl = lane & 15;
  const int kg = lane >> 4;

  bf16x8 qf[4];
  {
    const int tq = qbase + w * 16 + cl;
    const float* qp = qg + ((size_t)(b * SEQ + tq) * NHQ + hq) * DH;
#pragma unroll
    for (int dc = 0; dc < 4; ++dc) {
      const int d0 = dc * 32 + kg * 8;
      f32x4 x0 = *(const f32x4*)(qp + d0);
      f32x4 x1 = *(const f32x4*)(qp + d0 + 4);
      bf16x8 f;
#pragma unroll
      for (int j = 0; j < 4; ++j) { f[j] = (short)f2bf(x0[j] * SCALE); f[j + 4] = (short)f2bf(x1[j] * SCALE); }
      qf[dc] = f;
    }
  }

  f32x4 o[8];
#pragma unroll
  for (int i = 0; i < 8; ++i) o[i] = (f32x4){0.f, 0.f, 0.f, 0.f};
  float mrow[4] = {-1e30f, -1e30f, -1e30f, -1e30f};
  float lrow[4] = {0.f, 0.f, 0.f, 0.f};

  const int ntile = qt + 1;
  for (int t = 0; t < ntile; ++t) {
    __syncthreads();
    {
      const int nb   = btab[b * (SEQ / BSZ) + ((t * KVBLK) / BSZ)];
      const int off0 = (t * KVBLK) % BSZ;
      const int d4 = tid & 31;
      const int kl = tid >> 5;
      const float* kbp = kcache + (((size_t)nb * BSZ + off0) * NHK + hk) * DH + d4 * 4;
      const float* vbp = vcache + (((size_t)nb * BSZ + off0) * NHK + hk) * DH + d4 * 4;
#pragma unroll
      for (int p = 0; p < 8; ++p) {
        const int key = p * 8 + kl;
        const size_t go = (size_t)key * (NHK * DH);
        f32x4 kx = *(const f32x4*)(kbp + go);
        f32x4 vx = *(const f32x4*)(vbp + go);
        u32 w0 = (u32)f2bf(kx[0]) | ((u32)f2bf(kx[1]) << 16);
        u32 w1 = (u32)f2bf(kx[2]) | ((u32)f2bf(kx[3]) << 16);
        const int doff = (4 * d4) ^ ((key & 7) * 8);
        u64 pk = (u64)w0 | ((u64)w1 << 32);
        *(u64*)&lk[key * DH + doff] = pk;
#pragma unroll
        for (int j = 0; j < 4; ++j) {
          const int d = 4 * d4 + j;
          lv[d * KVBLK + (key ^ ((d & 7) * 8))] = f2bf(vx[j]);
        }
      }
    }
    __syncthreads();

    float s[4][4];
#pragma unroll
    for (int ct = 0; ct < 4; ++ct) {
      f32x4 acc = (f32x4){0.f, 0.f, 0.f, 0.f};
      const int key = ct * 16 + cl;
#pragma unroll
      for (int dc = 0; dc < 4; ++dc) {
        const int d0 = (dc * 32 + kg * 8) ^ ((key & 7) * 8);
        bf16x8 kf = *(const bf16x8*)&lk[key * DH + d0];
        acc = __builtin_amdgcn_mfma_f32_16x16x32_bf16(qf[dc], kf, acc, 0, 0, 0);
      }
#pragma unroll
      for (int v = 0; v < 4; ++v) s[ct][v] = acc[v];
    }
    if (t == qt) {
      const int rbase = w * 16 + kg * 4;
#pragma unroll
      for (int ct = 0; ct < 4; ++ct) {
        const int key = ct * 16 + cl;
#pragma unroll
        for (int v = 0; v < 4; ++v)
          if (key > rbase + v) s[ct][v] = -1e30f;
      }
    }
    float corr[4];
#pragma unroll
    for (int v = 0; v < 4; ++v) {
      float x = fmaxf(fmaxf(s[0][v], s[1][v]), fmaxf(s[2][v], s[3][v]));
#pragma unroll
      for (int off = 1; off < 16; off <<= 1) x = fmaxf(x, __shfl_xor(x, off));
      const float mn = fmaxf(mrow[v], x);
      corr[v] = __expf(mrow[v] - mn);
      mrow[v] = mn;
    }
    float rs[4] = {0.f, 0.f, 0.f, 0.f};
    u16 pb[4][4];
#pragma unroll
    for (int ct = 0; ct < 4; ++ct)
#pragma unroll
      for (int v = 0; v < 4; ++v) {
        const float p = __expf(s[ct][v] - mrow[v]);
        rs[v] += p;
        pb[ct][v] = f2bf(p);
      }
#pragma unroll
    for (int v = 0; v < 4; ++v) {
      float x = rs[v];
#pragma unroll
      for (int off = 1; off < 16; off <<= 1) x += __shfl_xor(x, off);
      lrow[v] = lrow[v] * corr[v] + x;
    }
#pragma unroll
    for (int dt = 0; dt < 8; ++dt)
#pragma unroll
      for (int v = 0; v < 4; ++v) o[dt][v] *= corr[v];

    u16* pw = &lp[w][0];
#pragma unroll
    for (int ct = 0; ct < 4; ++ct)
#pragma unroll
      for (int v = 0; v < 4; ++v) {
        const int r = kg * 4 + v;
        const int cc = ct * 16 + cl;
        pw[r * KVBLK + (cc ^ ((r & 7) * 8))] = pb[ct][v];
      }
    bf16x8 pa[2];
#pragma unroll
    for (int kc2 = 0; kc2 < 2; ++kc2) {
      const int c0 = (kc2 * 32 + kg * 8) ^ ((cl & 7) * 8);
      pa[kc2] = *(const bf16x8*)&pw[cl * KVBLK + c0];
    }
#pragma unroll
    for (int dt = 0; dt < 8; ++dt) {
      const int d = dt * 16 + cl;
#pragma unroll
      for (int kc2 = 0; kc2 < 2; ++kc2) {
        const int c0 = (kc2 * 32 + kg * 8) ^ ((d & 7) * 8);
        bf16x8 vf = *(const bf16x8*)&lv[d * KVBLK + c0];
        o[dt] = __builtin_amdgcn_mfma_f32_16x16x32_bf16(pa[kc2], vf, o[dt], 0, 0, 0);
      }
    }
  }

#pragma unroll
  for (int v = 0; v < 4; ++v) {
    const float inv = 1.0f / lrow[v];
    const int tq = qbase + w * 16 + kg * 4 + v;
    float* op = outg + ((size_t)(b * SEQ + tq) * NHQ + hq) * DH;
#pragma unroll
    for (int dt = 0; dt < 8; ++dt) op[dt * 16 + cl] = o[dt][v] * inv;
  }
}

extern "C" void kernel_launch(void* const* d_in, const int* in_sizes, int n_in,
                              void* d_out, int out_size, void* d_ws, size_t ws_size,
                              hipStream_t stream) {
  const float* q  = (const float*)d_in[0];
  const float* kc = (const float*)d_in[1];
  const float* vc = (const float*)d_in[2];
  const int*   bt = (const int*)d_in[3];
  float* out = (float*)d_out;
  const size_t kv_elems = (size_t)NBLK * NHK * BSZ * DH;   // 4.19M u16 each
  const size_t need = 2 * kv_elems * sizeof(u16);          // 16.8 MB
  if (ws_size >= need) {
    u16* kf = (u16*)d_ws;
    u16* vf = kf + kv_elems;
    const int total_quads = NBLK * BSZ * NHK * (DH / 4);
    prep_kv<<<total_quads / 256, 256, 0, stream>>>(kc, vc, kf, vf);
    attn_fwd_pre<<<dim3(1024), 256, 0, stream>>>(q, kf, vf, bt, out);
  } else {
    dim3 grid_fb(SEQ / 64, NHQ, 4 /*B*/);
    attn_fwd_fb<<<grid_fb, 256, 0, stream>>>(q, kc, vc, bt, out);
  }
}